// Round 1
// baseline (566.867 us; speedup 1.0000x reference)
//
#include <hip/hip_runtime.h>

typedef __bf16 bf16;
typedef __bf16 bf16x8 __attribute__((ext_vector_type(8)));
typedef float f32x4 __attribute__((ext_vector_type(4)));

#define MFMA16(a, b, c) __builtin_amdgcn_mfma_f32_16x16x32_bf16(a, b, c, 0, 0, 0)

static constexpr int Bn = 8;
static constexpr int Tn = 1024;
static constexpr int Cn = 1024;
static constexpr int Hn = 16;

// ---------------------------------------------------------------------------
// Transpose + cast fp32 [K][N] -> bf16 [N][K]
// ---------------------------------------------------------------------------
__global__ __launch_bounds__(256) void tcast(const float* __restrict__ in,
                                             bf16* __restrict__ out,
                                             int K, int N) {
    __shared__ float tile[32][33];
    const int n0 = blockIdx.x * 32, k0 = blockIdx.y * 32;
    const int tx = threadIdx.x & 31, ty = threadIdx.x >> 5;  // 32 x 8
#pragma unroll
    for (int i = 0; i < 4; i++)
        tile[ty + 8 * i][tx] = in[(size_t)(k0 + ty + 8 * i) * N + n0 + tx];
    __syncthreads();
#pragma unroll
    for (int i = 0; i < 4; i++)
        out[(size_t)(n0 + ty + 8 * i) * K + k0 + tx] = (bf16)tile[tx][ty + 8 * i];
}

// ---------------------------------------------------------------------------
// LayerNorm fp32 row -> bf16 row. One block per row of C=1024.
// ---------------------------------------------------------------------------
__global__ __launch_bounds__(256) void ln_bf16(const float* __restrict__ x,
                                               const float* __restrict__ g,
                                               const float* __restrict__ be,
                                               bf16* __restrict__ out) {
    const int row = blockIdx.x, t = threadIdx.x;
    const float* xr = x + (size_t)row * Cn;
    float v[4], s = 0.f, s2 = 0.f;
#pragma unroll
    for (int i = 0; i < 4; i++) {
        v[i] = xr[t + i * 256];
        s += v[i];
        s2 += v[i] * v[i];
    }
#pragma unroll
    for (int off = 32; off > 0; off >>= 1) {
        s += __shfl_down(s, off);
        s2 += __shfl_down(s2, off);
    }
    __shared__ float red[8];
    const int wave = t >> 6, lane = t & 63;
    if (lane == 0) {
        red[wave] = s;
        red[4 + wave] = s2;
    }
    __syncthreads();
    s = red[0] + red[1] + red[2] + red[3];
    s2 = red[4] + red[5] + red[6] + red[7];
    const float mu = s * (1.f / Cn);
    const float rstd = rsqrtf(s2 * (1.f / Cn) - mu * mu + 1e-5f);
    bf16* orow = out + (size_t)row * Cn;
#pragma unroll
    for (int i = 0; i < 4; i++) {
        int c = t + i * 256;
        orow[c] = (bf16)((v[i] - mu) * rstd * g[c] + be[c]);
    }
}

// ---------------------------------------------------------------------------
// GEMM: out[M,N] = A[M,K] @ Bt[N,K]^T + bias (+ relu) (+ resid)
// 128x128 tile, BK=32, 4 waves (2x2), each wave 4x4 MFMA 16x16x32 tiles.
// ---------------------------------------------------------------------------
template <bool RELU, bool RESID, bool OUTBF16>
__global__ __launch_bounds__(256, 2) void gemm_bt(const bf16* __restrict__ A,
                                                  const bf16* __restrict__ Bt,
                                                  const float* __restrict__ bias,
                                                  const float* __restrict__ resid,
                                                  void* __restrict__ outp,
                                                  int M, int N, int K) {
    __shared__ bf16 As[128 * 32];
    __shared__ bf16 Bs[128 * 32];
    const int t = threadIdx.x;
    const int lane = t & 63, wave = t >> 6;
    const int lane15 = lane & 15, quad = lane >> 4;
    const int m0 = blockIdx.x * 128, n0 = blockIdx.y * 128;
    const int mb = (wave >> 1) * 64, nb = (wave & 1) * 64;

    const f32x4 zero4 = {0.f, 0.f, 0.f, 0.f};
    f32x4 acc[4][4];
#pragma unroll
    for (int i = 0; i < 4; i++)
#pragma unroll
        for (int j = 0; j < 4; j++) acc[i][j] = zero4;

    const int arow = t >> 2, akk = (t & 3) * 8;  // 64 rows/iter, 2 iters
    const size_t a_off0 = (size_t)(m0 + arow) * K + akk;
    const size_t b_off0 = (size_t)(n0 + arow) * K + akk;

    for (int kt = 0; kt < K; kt += 32) {
        bf16x8 av0 = *(const bf16x8*)(A + a_off0 + kt);
        bf16x8 av1 = *(const bf16x8*)(A + a_off0 + (size_t)64 * K + kt);
        bf16x8 bv0 = *(const bf16x8*)(Bt + b_off0 + kt);
        bf16x8 bv1 = *(const bf16x8*)(Bt + b_off0 + (size_t)64 * K + kt);
        *(bf16x8*)(As + arow * 32 + akk) = av0;
        *(bf16x8*)(As + (arow + 64) * 32 + akk) = av1;
        *(bf16x8*)(Bs + arow * 32 + akk) = bv0;
        *(bf16x8*)(Bs + (arow + 64) * 32 + akk) = bv1;
        __syncthreads();
        bf16x8 fa[4], fb[4];
#pragma unroll
        for (int mi = 0; mi < 4; mi++)
            fa[mi] = *(const bf16x8*)(As + (mb + mi * 16 + lane15) * 32 + quad * 8);
#pragma unroll
        for (int ni = 0; ni < 4; ni++)
            fb[ni] = *(const bf16x8*)(Bs + (nb + ni * 16 + lane15) * 32 + quad * 8);
#pragma unroll
        for (int mi = 0; mi < 4; mi++)
#pragma unroll
            for (int ni = 0; ni < 4; ni++)
                acc[mi][ni] = MFMA16(fa[mi], fb[ni], acc[mi][ni]);
        __syncthreads();
    }

    float bsv[4];
#pragma unroll
    for (int ni = 0; ni < 4; ni++) bsv[ni] = bias[n0 + nb + ni * 16 + lane15];
#pragma unroll
    for (int mi = 0; mi < 4; mi++) {
#pragma unroll
        for (int reg = 0; reg < 4; reg++) {
            const int row = m0 + mb + mi * 16 + quad * 4 + reg;
#pragma unroll
            for (int ni = 0; ni < 4; ni++) {
                const int col = n0 + nb + ni * 16 + lane15;
                float v = acc[mi][ni][reg] + bsv[ni];
                if (RELU) v = v > 0.f ? v : 0.f;
                if (RESID) v += resid[(size_t)row * N + col];
                if (OUTBF16)
                    ((bf16*)outp)[(size_t)row * N + col] = (bf16)v;
                else
                    ((float*)outp)[(size_t)row * N + col] = v;
            }
        }
    }
}

// ---------------------------------------------------------------------------
// Flash attention, causal. qkv bf16 [B*T, 3C] (q|k|v each H*64 wide).
// Block: 256 thr = 4 waves; one block per (b,h) x 64 q-rows; wave owns 16 rows.
// K-blocks of 32. MFMA 16x16x32 for QK^T and PV.
// ---------------------------------------------------------------------------
__global__ __launch_bounds__(256) void attn(const bf16* __restrict__ qkv,
                                            bf16* __restrict__ y) {
    __shared__ bf16 Ks[32 * 64];
    __shared__ bf16 Vt[64 * 32];
    __shared__ bf16 Ps[4][16 * 32];
    const int t = threadIdx.x, lane = t & 63, wave = t >> 6;
    const int lane15 = lane & 15, quad = lane >> 4;
    const int bh = blockIdx.x, b = bh >> 4, h = bh & 15;
    const int q0 = blockIdx.y * 64;
    const float scale = 0.07216878364870323f;  // 1/sqrt(3*C/H) = 1/sqrt(192)
    const float NEG_INF = -__builtin_inff();

    const size_t qbase = ((size_t)(b * Tn + q0 + wave * 16 + lane15)) * 3072 + h * 64;
    const bf16x8 fq0 = *(const bf16x8*)(qkv + qbase + quad * 8);
    const bf16x8 fq1 = *(const bf16x8*)(qkv + qbase + 32 + quad * 8);

    const f32x4 zero4 = {0.f, 0.f, 0.f, 0.f};
    f32x4 o[4];
#pragma unroll
    for (int i = 0; i < 4; i++) o[i] = zero4;
    float m_r[4], l_r[4];
#pragma unroll
    for (int r = 0; r < 4; r++) {
        m_r[r] = NEG_INF;
        l_r[r] = 0.f;
    }

    const int nkb = q0 / 32 + 2;
    const int srow = t >> 3, scol = (t & 7) * 8;
    for (int kb = 0; kb < nkb; kb++) {
        const int k0 = kb * 32;
        const size_t kvrow = ((size_t)(b * Tn + k0 + srow)) * 3072 + h * 64 + scol;
        bf16x8 kv = *(const bf16x8*)(qkv + kvrow + Cn);
        *(bf16x8*)(Ks + srow * 64 + scol) = kv;
        bf16x8 vv = *(const bf16x8*)(qkv + kvrow + 2 * Cn);
#pragma unroll
        for (int i = 0; i < 8; i++) Vt[(scol + i) * 32 + srow] = vv[i];
        __syncthreads();

        if (k0 <= q0 + wave * 16 + 15) {  // wave-uniform causal skip
            f32x4 s0 = zero4, s1 = zero4;
            bf16x8 fk;
            fk = *(const bf16x8*)(Ks + lane15 * 64 + quad * 8);
            s0 = MFMA16(fq0, fk, s0);
            fk = *(const bf16x8*)(Ks + lane15 * 64 + 32 + quad * 8);
            s0 = MFMA16(fq1, fk, s0);
            fk = *(const bf16x8*)(Ks + (16 + lane15) * 64 + quad * 8);
            s1 = MFMA16(fq0, fk, s1);
            fk = *(const bf16x8*)(Ks + (16 + lane15) * 64 + 32 + quad * 8);
            s1 = MFMA16(fq1, fk, s1);

            float sv[2][4], p[2][4];
            const int rg_base = q0 + wave * 16 + quad * 4;
#pragma unroll
            for (int r = 0; r < 4; r++) {
                float x0 = s0[r] * scale;
                if (k0 + lane15 > rg_base + r) x0 = NEG_INF;
                float x1 = s1[r] * scale;
                if (k0 + 16 + lane15 > rg_base + r) x1 = NEG_INF;
                sv[0][r] = x0;
                sv[1][r] = x1;
            }
            float alpha[4];
#pragma unroll
            for (int r = 0; r < 4; r++) {
                float mt = fmaxf(sv[0][r], sv[1][r]);
                mt = fmaxf(mt, __shfl_xor(mt, 1));
                mt = fmaxf(mt, __shfl_xor(mt, 2));
                mt = fmaxf(mt, __shfl_xor(mt, 4));
                mt = fmaxf(mt, __shfl_xor(mt, 8));
                const float mn = fmaxf(m_r[r], mt);
                alpha[r] = __expf(m_r[r] - mn);
                p[0][r] = __expf(sv[0][r] - mn);
                p[1][r] = __expf(sv[1][r] - mn);
                float rs = p[0][r] + p[1][r];
                rs += __shfl_xor(rs, 1);
                rs += __shfl_xor(rs, 2);
                rs += __shfl_xor(rs, 4);
                rs += __shfl_xor(rs, 8);
                l_r[r] = l_r[r] * alpha[r] + rs;
                m_r[r] = mn;
            }
#pragma unroll
            for (int ni = 0; ni < 4; ni++)
#pragma unroll
                for (int r = 0; r < 4; r++) o[ni][r] *= alpha[r];
            // P (C-layout) -> LDS -> A-layout (same-wave round trip)
#pragma unroll
            for (int c = 0; c < 2; c++)
#pragma unroll
                for (int r = 0; r < 4; r++)
                    Ps[wave][(quad * 4 + r) * 32 + c * 16 + lane15] = (bf16)p[c][r];
            const bf16x8 fp = *(const bf16x8*)(&Ps[wave][lane15 * 32 + quad * 8]);
#pragma unroll
            for (int ni = 0; ni < 4; ni++) {
                const bf16x8 fv = *(const bf16x8*)(Vt + (ni * 16 + lane15) * 32 + quad * 8);
                o[ni] = MFMA16(fp, fv, o[ni]);
            }
        }
        __syncthreads();
    }

#pragma unroll
    for (int r = 0; r < 4; r++) {
        const float inv = 1.f / l_r[r];
        const int row = q0 + wave * 16 + quad * 4 + r;
        const size_t base = ((size_t)(b * Tn + row)) * Cn + h * 64;
#pragma unroll
        for (int ni = 0; ni < 4; ni++)
            y[base + ni * 16 + lane15] = (bf16)(o[ni][r] * inv);
    }
}

// ---------------------------------------------------------------------------
extern "C" void kernel_launch(void* const* d_in, const int* in_sizes, int n_in,
                              void* d_out, int out_size, void* d_ws, size_t ws_size,
                              hipStream_t stream) {
    const float* x = (const float*)d_in[0];
    const float* Wqkv = (const float*)d_in[1];
    const float* bqkv = (const float*)d_in[2];
    const float* Wproj = (const float*)d_in[3];
    const float* bproj = (const float*)d_in[4];
    const float* ln1g = (const float*)d_in[5];
    const float* ln1b = (const float*)d_in[6];
    const float* ln2g = (const float*)d_in[7];
    const float* ln2b = (const float*)d_in[8];
    const float* W1 = (const float*)d_in[9];
    const float* b1 = (const float*)d_in[10];
    const float* W2 = (const float*)d_in[11];
    const float* b2 = (const float*)d_in[12];
    float* out = (float*)d_out;

    char* ws = (char*)d_ws;
    size_t off = 0;
    auto alloc = [&](size_t bytes) {
        void* p = ws + off;
        off += (bytes + 255) & ~(size_t)255;
        return p;
    };
    bf16* WqkvT = (bf16*)alloc((size_t)3072 * 1024 * 2);
    bf16* WprojT = (bf16*)alloc((size_t)1024 * 1024 * 2);
    bf16* W1T = (bf16*)alloc((size_t)4096 * 1024 * 2);
    bf16* W2T = (bf16*)alloc((size_t)1024 * 4096 * 2);
    bf16* hbuf = (bf16*)alloc((size_t)8192 * 1024 * 2);
    bf16* qkvb = (bf16*)alloc((size_t)8192 * 3072 * 2);
    bf16* ybuf = (bf16*)alloc((size_t)8192 * 1024 * 2);
    float* x1 = (float*)alloc((size_t)8192 * 1024 * 4);
    bf16* a1 = qkvb;  // reuse qkv(48MB)+y(16MB) region for a1 (64MB); both dead by GEMM3

    // weights -> bf16 transposed
    tcast<<<dim3(3072 / 32, 1024 / 32), 256, 0, stream>>>(Wqkv, WqkvT, 1024, 3072);
    tcast<<<dim3(1024 / 32, 1024 / 32), 256, 0, stream>>>(Wproj, WprojT, 1024, 1024);
    tcast<<<dim3(4096 / 32, 1024 / 32), 256, 0, stream>>>(W1, W1T, 1024, 4096);
    tcast<<<dim3(1024 / 32, 4096 / 32), 256, 0, stream>>>(W2, W2T, 4096, 1024);

    // LN1 -> h
    ln_bf16<<<8192, 256, 0, stream>>>(x, ln1g, ln1b, hbuf);
    // qkv = h @ Wqkv + bqkv  (bf16 out)
    gemm_bt<false, false, true><<<dim3(64, 24), 256, 0, stream>>>(
        hbuf, WqkvT, bqkv, nullptr, qkvb, 8192, 3072, 1024);
    // attention -> y (bf16, [B,T,C])
    attn<<<dim3(Bn * Hn, Tn / 64), 256, 0, stream>>>(qkvb, ybuf);
    // x1 = x + y @ Wproj + bproj  (fp32)
    gemm_bt<false, true, false><<<dim3(64, 8), 256, 0, stream>>>(
        ybuf, WprojT, bproj, x, x1, 8192, 1024, 1024);
    // LN2 -> h
    ln_bf16<<<8192, 256, 0, stream>>>(x1, ln2g, ln2b, hbuf);
    // a1 = relu(h @ W1 + b1)  (bf16)
    gemm_bt<true, false, true><<<dim3(64, 32), 256, 0, stream>>>(
        hbuf, W1T, b1, nullptr, a1, 8192, 4096, 1024);
    // out = x1 + a1 @ W2 + b2  (fp32)
    gemm_bt<false, true, false><<<dim3(64, 8), 256, 0, stream>>>(
        a1, W2T, b2, x1, out, 8192, 1024, 4096);
}

// Round 2
// 502.678 us; speedup vs baseline: 1.1277x; 1.1277x over previous
//
#include <hip/hip_runtime.h>

typedef __bf16 bf16;
typedef __bf16 bf16x8 __attribute__((ext_vector_type(8)));
typedef float f32x4 __attribute__((ext_vector_type(4)));

#define MFMA16(a, b, c) __builtin_amdgcn_mfma_f32_16x16x32_bf16(a, b, c, 0, 0, 0)

static constexpr int Bn = 8;
static constexpr int Tn = 1024;
static constexpr int Cn = 1024;
static constexpr int Hn = 16;

typedef const __attribute__((address_space(1))) unsigned int* gp_t;
typedef __attribute__((address_space(3))) unsigned int* lp_t;
__device__ __forceinline__ void gload_lds16(const bf16* g, bf16* l) {
    __builtin_amdgcn_global_load_lds((gp_t)(const void*)g, (lp_t)(void*)l, 16, 0, 0);
}

// ---------------------------------------------------------------------------
// Transpose + cast fp32 [K][N] -> bf16 [N][K]
// ---------------------------------------------------------------------------
__global__ __launch_bounds__(256) void tcast(const float* __restrict__ in,
                                             bf16* __restrict__ out,
                                             int K, int N) {
    __shared__ float tile[32][33];
    const int n0 = blockIdx.x * 32, k0 = blockIdx.y * 32;
    const int tx = threadIdx.x & 31, ty = threadIdx.x >> 5;  // 32 x 8
#pragma unroll
    for (int i = 0; i < 4; i++)
        tile[ty + 8 * i][tx] = in[(size_t)(k0 + ty + 8 * i) * N + n0 + tx];
    __syncthreads();
#pragma unroll
    for (int i = 0; i < 4; i++)
        out[(size_t)(n0 + ty + 8 * i) * K + k0 + tx] = (bf16)tile[tx][ty + 8 * i];
}

// ---------------------------------------------------------------------------
// LayerNorm fp32 row -> bf16 row. One block per row of C=1024.
// ---------------------------------------------------------------------------
__global__ __launch_bounds__(256) void ln_bf16(const float* __restrict__ x,
                                               const float* __restrict__ g,
                                               const float* __restrict__ be,
                                               bf16* __restrict__ out) {
    const int row = blockIdx.x, t = threadIdx.x;
    const float* xr = x + (size_t)row * Cn;
    float v[4], s = 0.f, s2 = 0.f;
#pragma unroll
    for (int i = 0; i < 4; i++) {
        v[i] = xr[t + i * 256];
        s += v[i];
        s2 += v[i] * v[i];
    }
#pragma unroll
    for (int off = 32; off > 0; off >>= 1) {
        s += __shfl_down(s, off);
        s2 += __shfl_down(s2, off);
    }
    __shared__ float red[8];
    const int wave = t >> 6, lane = t & 63;
    if (lane == 0) {
        red[wave] = s;
        red[4 + wave] = s2;
    }
    __syncthreads();
    s = red[0] + red[1] + red[2] + red[3];
    s2 = red[4] + red[5] + red[6] + red[7];
    const float mu = s * (1.f / Cn);
    const float rstd = rsqrtf(s2 * (1.f / Cn) - mu * mu + 1e-5f);
    bf16* orow = out + (size_t)row * Cn;
#pragma unroll
    for (int i = 0; i < 4; i++) {
        int c = t + i * 256;
        orow[c] = (bf16)((v[i] - mu) * rstd * g[c] + be[c]);
    }
}

// ---------------------------------------------------------------------------
// V transpose: qkv v-part [B,T,H,64] -> Vt [B,H,64,T]
// ---------------------------------------------------------------------------
__global__ __launch_bounds__(256) void vtrans(const bf16* __restrict__ qkv,
                                              bf16* __restrict__ Vt) {
    __shared__ bf16 tile[64 * 72];
    const int tid = threadIdx.x;
    const int bh = blockIdx.x, b = bh >> 4, h = bh & 15;
    const int t0 = blockIdx.y * 64;
    const int r = tid >> 3, c = (tid & 7) * 8;
#pragma unroll
    for (int i = 0; i < 2; i++) {
        const int rr = r + i * 32;  // token within tile
        *(bf16x8*)(tile + rr * 72 + c) =
            *(const bf16x8*)(qkv + ((size_t)(b * Tn + t0 + rr)) * 3072 + 2 * Cn + h * 64 + c);
    }
    __syncthreads();
#pragma unroll
    for (int i = 0; i < 2; i++) {
        const int d = r + i * 32;
        bf16x8 v;
#pragma unroll
        for (int j = 0; j < 8; j++) v[j] = tile[(c + j) * 72 + d];
        *(bf16x8*)(Vt + ((size_t)bh * 64 + d) * Tn + t0 + c) = v;
    }
}

// ---------------------------------------------------------------------------
// GEMM: out[M,N] = A[M,K] @ Bt[N,K]^T + bias (+ relu) (+ resid)
// 128x128 tile, BK=32, 4 waves (2x2), global_load_lds width-16 staging (m97).
// ---------------------------------------------------------------------------
template <bool RELU, bool RESID, bool OUTBF16>
__global__ __launch_bounds__(256) void gemm_bt(const bf16* __restrict__ A,
                                               const bf16* __restrict__ Bt,
                                               const float* __restrict__ bias,
                                               const float* __restrict__ resid,
                                               void* __restrict__ outp,
                                               int M, int N, int K) {
    __shared__ __align__(16) bf16 As[128 * 32];
    __shared__ __align__(16) bf16 Bs[128 * 32];
    const int t = threadIdx.x;
    const int lane = t & 63, wave = t >> 6;
    const int lane15 = lane & 15, quad = lane >> 4;
    const int m0 = blockIdx.x * 128, n0 = blockIdx.y * 128;
    const int mb = (wave >> 1) * 64, nb = (wave & 1) * 64;

    const f32x4 zero4 = {0.f, 0.f, 0.f, 0.f};
    f32x4 acc[4][4];
#pragma unroll
    for (int i = 0; i < 4; i++)
#pragma unroll
        for (int j = 0; j < 4; j++) acc[i][j] = zero4;

    // staging map: wave w covers rows [w*16, w*16+16) and +64; lane -> row w*16+(l>>2), col (l&3)*8
    const int r16 = lane >> 2, c8 = (lane & 3) * 8;
    const bf16* gA0 = A + (size_t)(m0 + wave * 16 + r16) * K + c8;
    const bf16* gA1 = gA0 + (size_t)64 * K;
    const bf16* gB0 = Bt + (size_t)(n0 + wave * 16 + r16) * K + c8;
    const bf16* gB1 = gB0 + (size_t)64 * K;
    bf16* lA0 = As + wave * 512;
    bf16* lA1 = As + 2048 + wave * 512;
    bf16* lB0 = Bs + wave * 512;
    bf16* lB1 = Bs + 2048 + wave * 512;

    for (int kt = 0; kt < K; kt += 32) {
        gload_lds16(gA0 + kt, lA0);
        gload_lds16(gA1 + kt, lA1);
        gload_lds16(gB0 + kt, lB0);
        gload_lds16(gB1 + kt, lB1);
        __syncthreads();
        bf16x8 fa[4], fb[4];
#pragma unroll
        for (int mi = 0; mi < 4; mi++)
            fa[mi] = *(const bf16x8*)(As + (mb + mi * 16 + lane15) * 32 + quad * 8);
#pragma unroll
        for (int ni = 0; ni < 4; ni++)
            fb[ni] = *(const bf16x8*)(Bs + (nb + ni * 16 + lane15) * 32 + quad * 8);
#pragma unroll
        for (int mi = 0; mi < 4; mi++)
#pragma unroll
            for (int ni = 0; ni < 4; ni++)
                acc[mi][ni] = MFMA16(fa[mi], fb[ni], acc[mi][ni]);
        __syncthreads();
    }

    float bsv[4];
#pragma unroll
    for (int ni = 0; ni < 4; ni++) bsv[ni] = bias[n0 + nb + ni * 16 + lane15];
#pragma unroll
    for (int mi = 0; mi < 4; mi++) {
#pragma unroll
        for (int reg = 0; reg < 4; reg++) {
            const int row = m0 + mb + mi * 16 + quad * 4 + reg;
#pragma unroll
            for (int ni = 0; ni < 4; ni++) {
                const int col = n0 + nb + ni * 16 + lane15;
                float v = acc[mi][ni][reg] + bsv[ni];
                if (RELU) v = v > 0.f ? v : 0.f;
                if (RESID) v += resid[(size_t)row * N + col];
                if (OUTBF16)
                    ((bf16*)outp)[(size_t)row * N + col] = (bf16)v;
                else
                    ((float*)outp)[(size_t)row * N + col] = v;
            }
        }
    }
}

// ---------------------------------------------------------------------------
// Flash attention, causal. Q-tile 128 rows/block (32/wave), K-block 64.
// No max-tracking (bounded logits, exp2 domain); row-sum via ones-row in V.
// qkv bf16 [B*T, 3C]; Vt bf16 [B,H,64,T].
// ---------------------------------------------------------------------------
__global__ __launch_bounds__(256) void attn(const bf16* __restrict__ qkv,
                                            const bf16* __restrict__ Vt,
                                            bf16* __restrict__ y) {
    __shared__ __align__(16) bf16 Ks[64 * 72];       // [key][d] padded
    __shared__ __align__(16) bf16 Vs[80 * 72];       // [d][key] padded; rows 64..79: ones/zeros
    __shared__ __align__(16) bf16 Ps[4][32 * 72];    // per-wave P tile [qrow][key]
    const int tid = threadIdx.x, lane = tid & 63, wave = tid >> 6;
    const int lane15 = lane & 15, quad = lane >> 4;
    const int b = blockIdx.x >> 4, h = blockIdx.x & 15;
    const int q0 = blockIdx.y * 128;
    const int qr0 = q0 + wave * 32;
    const float c1 = 0.10412043f;  // (1/sqrt(192)) * log2(e)

    // ones row (d=64) for row-sum trick; rows 65..79 zero
    for (int i = tid; i < 16 * 72; i += 256)
        Vs[64 * 72 + i] = (bf16)((i < 72) ? 1.0f : 0.0f);

    // Q fragments: 2 m-tiles x 2 k-chunks (A-layout)
    bf16x8 fq[2][2];
#pragma unroll
    for (int mi = 0; mi < 2; mi++) {
        const size_t qb = ((size_t)(b * Tn + qr0 + mi * 16 + lane15)) * 3072 + h * 64;
#pragma unroll
        for (int kk = 0; kk < 2; kk++)
            fq[mi][kk] = *(const bf16x8*)(qkv + qb + kk * 32 + quad * 8);
    }

    const f32x4 zero4 = {0.f, 0.f, 0.f, 0.f};
    f32x4 o[2][4], lacc[2];
#pragma unroll
    for (int mi = 0; mi < 2; mi++) {
        lacc[mi] = zero4;
#pragma unroll
        for (int ni = 0; ni < 4; ni++) o[mi][ni] = zero4;
    }

    const int sr = tid >> 3, sc = (tid & 7) * 8;
    const int nkb = q0 / 64 + 2;
    for (int kb = 0; kb < nkb; kb++) {
        const int k0 = kb * 64;
#pragma unroll
        for (int i = 0; i < 2; i++) {
            const int r = sr + i * 32;
            *(bf16x8*)(Ks + r * 72 + sc) =
                *(const bf16x8*)(qkv + ((size_t)(b * Tn + k0 + r)) * 3072 + Cn + h * 64 + sc);
            *(bf16x8*)(Vs + r * 72 + sc) =
                *(const bf16x8*)(Vt + ((size_t)blockIdx.x * 64 + r) * Tn + k0 + sc);
        }
        __syncthreads();

        if (k0 <= qr0 + 31) {
            // S = Q K^T  (16 MFMA)
            bf16x8 fk[4][2];
#pragma unroll
            for (int ni = 0; ni < 4; ni++)
#pragma unroll
                for (int kk = 0; kk < 2; kk++)
                    fk[ni][kk] = *(const bf16x8*)(Ks + (ni * 16 + lane15) * 72 + kk * 32 + quad * 8);
            f32x4 s[2][4];
#pragma unroll
            for (int mi = 0; mi < 2; mi++)
#pragma unroll
                for (int ni = 0; ni < 4; ni++) {
                    f32x4 a = zero4;
                    a = MFMA16(fq[mi][0], fk[ni][0], a);
                    a = MFMA16(fq[mi][1], fk[ni][1], a);
                    s[mi][ni] = a;
                }
            // p = exp2(s*c1) (+ causal mask), store to Ps
            const bool domask = (k0 + 63 > qr0);
            if (domask) {
#pragma unroll
                for (int mi = 0; mi < 2; mi++)
#pragma unroll
                    for (int ni = 0; ni < 4; ni++)
#pragma unroll
                        for (int r = 0; r < 4; r++) {
                            const int key = k0 + ni * 16 + lane15;
                            const int row = qr0 + mi * 16 + quad * 4 + r;
                            float L = (key > row) ? -1e30f : s[mi][ni][r] * c1;
                            Ps[wave][(mi * 16 + quad * 4 + r) * 72 + ni * 16 + lane15] =
                                (bf16)__builtin_amdgcn_exp2f(L);
                        }
            } else {
#pragma unroll
                for (int mi = 0; mi < 2; mi++)
#pragma unroll
                    for (int ni = 0; ni < 4; ni++)
#pragma unroll
                        for (int r = 0; r < 4; r++)
                            Ps[wave][(mi * 16 + quad * 4 + r) * 72 + ni * 16 + lane15] =
                                (bf16)__builtin_amdgcn_exp2f(s[mi][ni][r] * c1);
            }
            // PV (+ row-sum via ones-row): 20 MFMA
            bf16x8 fp[2][2];
#pragma unroll
            for (int mi = 0; mi < 2; mi++)
#pragma unroll
                for (int kk = 0; kk < 2; kk++)
                    fp[mi][kk] = *(const bf16x8*)(&Ps[wave][(mi * 16 + lane15) * 72 + kk * 32 + quad * 8]);
#pragma unroll
            for (int ni = 0; ni < 5; ni++) {
                bf16x8 fv0 = *(const bf16x8*)(Vs + (ni * 16 + lane15) * 72 + quad * 8);
                bf16x8 fv1 = *(const bf16x8*)(Vs + (ni * 16 + lane15) * 72 + 32 + quad * 8);
#pragma unroll
                for (int mi = 0; mi < 2; mi++) {
                    f32x4* dst = (ni < 4) ? &o[mi][ni] : &lacc[mi];
                    f32x4 a = *dst;
                    a = MFMA16(fp[mi][0], fv0, a);
                    a = MFMA16(fp[mi][1], fv1, a);
                    *dst = a;
                }
            }
        }
        __syncthreads();
    }

#pragma unroll
    for (int mi = 0; mi < 2; mi++)
#pragma unroll
        for (int r = 0; r < 4; r++) {
            float l = __shfl(lacc[mi][r], lane & 48);  // col 64 lives at lane15==0 of own quad
            const float inv = 1.f / l;
            const size_t base = ((size_t)(b * Tn + qr0 + mi * 16 + quad * 4 + r)) * Cn + h * 64;
#pragma unroll
            for (int ni = 0; ni < 4; ni++)
                y[base + ni * 16 + lane15] = (bf16)(o[mi][ni][r] * inv);
        }
}

// ---------------------------------------------------------------------------
extern "C" void kernel_launch(void* const* d_in, const int* in_sizes, int n_in,
                              void* d_out, int out_size, void* d_ws, size_t ws_size,
                              hipStream_t stream) {
    const float* x = (const float*)d_in[0];
    const float* Wqkv = (const float*)d_in[1];
    const float* bqkv = (const float*)d_in[2];
    const float* Wproj = (const float*)d_in[3];
    const float* bproj = (const float*)d_in[4];
    const float* ln1g = (const float*)d_in[5];
    const float* ln1b = (const float*)d_in[6];
    const float* ln2g = (const float*)d_in[7];
    const float* ln2b = (const float*)d_in[8];
    const float* W1 = (const float*)d_in[9];
    const float* b1 = (const float*)d_in[10];
    const float* W2 = (const float*)d_in[11];
    const float* b2 = (const float*)d_in[12];
    float* out = (float*)d_out;

    char* ws = (char*)d_ws;
    size_t off = 0;
    auto alloc = [&](size_t bytes) {
        void* p = ws + off;
        off += (bytes + 255) & ~(size_t)255;
        return p;
    };
    bf16* WqkvT = (bf16*)alloc((size_t)3072 * 1024 * 2);
    bf16* WprojT = (bf16*)alloc((size_t)1024 * 1024 * 2);
    bf16* W1T = (bf16*)alloc((size_t)4096 * 1024 * 2);
    bf16* W2T = (bf16*)alloc((size_t)1024 * 4096 * 2);
    bf16* hbuf = (bf16*)alloc((size_t)8192 * 1024 * 2);
    bf16* qkvb = (bf16*)alloc((size_t)8192 * 3072 * 2);
    bf16* ybuf = (bf16*)alloc((size_t)8192 * 1024 * 2);
    bf16* vtb = (bf16*)alloc((size_t)8192 * 1024 * 2);
    float* x1 = (float*)alloc((size_t)8192 * 1024 * 4);
    bf16* a1 = qkvb;  // reuse qkv region for a1; dead by GEMM3

    // weights -> bf16 transposed
    tcast<<<dim3(3072 / 32, 1024 / 32), 256, 0, stream>>>(Wqkv, WqkvT, 1024, 3072);
    tcast<<<dim3(1024 / 32, 1024 / 32), 256, 0, stream>>>(Wproj, WprojT, 1024, 1024);
    tcast<<<dim3(4096 / 32, 1024 / 32), 256, 0, stream>>>(W1, W1T, 1024, 4096);
    tcast<<<dim3(1024 / 32, 4096 / 32), 256, 0, stream>>>(W2, W2T, 4096, 1024);

    // LN1 -> h
    ln_bf16<<<8192, 256, 0, stream>>>(x, ln1g, ln1b, hbuf);
    // qkv = h @ Wqkv + bqkv  (bf16 out)
    gemm_bt<false, false, true><<<dim3(64, 24), 256, 0, stream>>>(
        hbuf, WqkvT, bqkv, nullptr, qkvb, 8192, 3072, 1024);
    // V -> Vt [B,H,64,T]
    vtrans<<<dim3(Bn * Hn, Tn / 64), 256, 0, stream>>>(qkvb, vtb);
    // attention -> y (bf16, [B,T,C])
    attn<<<dim3(Bn * Hn, Tn / 128), 256, 0, stream>>>(qkvb, vtb, ybuf);
    // x1 = x + y @ Wproj + bproj  (fp32)
    gemm_bt<false, true, false><<<dim3(64, 8), 256, 0, stream>>>(
        ybuf, WprojT, bproj, x, x1, 8192, 1024, 1024);
    // LN2 -> h
    ln_bf16<<<8192, 256, 0, stream>>>(x1, ln2g, ln2b, hbuf);
    // a1 = relu(h @ W1 + b1)  (bf16)
    gemm_bt<true, false, true><<<dim3(64, 32), 256, 0, stream>>>(
        hbuf, W1T, b1, nullptr, a1, 8192, 4096, 1024);
    // out = x1 + a1 @ W2 + b2  (fp32)
    gemm_bt<false, true, false><<<dim3(64, 8), 256, 0, stream>>>(
        a1, W2T, b2, x1, out, 8192, 1024, 4096);
}

// Round 3
// 469.091 us; speedup vs baseline: 1.2084x; 1.0716x over previous
//
#include <hip/hip_runtime.h>

typedef __bf16 bf16;
typedef __bf16 bf16x8 __attribute__((ext_vector_type(8)));
typedef float f32x4 __attribute__((ext_vector_type(4)));

#define MFMA16(a, b, c) __builtin_amdgcn_mfma_f32_16x16x32_bf16(a, b, c, 0, 0, 0)

static constexpr int Bn = 8;
static constexpr int Tn = 1024;
static constexpr int Cn = 1024;
static constexpr int Hn = 16;

typedef const __attribute__((address_space(1))) unsigned int* gp_t;
typedef __attribute__((address_space(3))) unsigned int* lp_t;
__device__ __forceinline__ void gload_lds16(const bf16* g, bf16* l) {
    __builtin_amdgcn_global_load_lds((gp_t)(const void*)g, (lp_t)(void*)l, 16, 0, 0);
}

// ---------------------------------------------------------------------------
// Transpose + cast fp32 [K][N] -> bf16 [N][K]
// ---------------------------------------------------------------------------
__global__ __launch_bounds__(256) void tcast(const float* __restrict__ in,
                                             bf16* __restrict__ out,
                                             int K, int N) {
    __shared__ float tile[32][33];
    const int n0 = blockIdx.x * 32, k0 = blockIdx.y * 32;
    const int tx = threadIdx.x & 31, ty = threadIdx.x >> 5;  // 32 x 8
#pragma unroll
    for (int i = 0; i < 4; i++)
        tile[ty + 8 * i][tx] = in[(size_t)(k0 + ty + 8 * i) * N + n0 + tx];
    __syncthreads();
#pragma unroll
    for (int i = 0; i < 4; i++)
        out[(size_t)(n0 + ty + 8 * i) * K + k0 + tx] = (bf16)tile[tx][ty + 8 * i];
}

// ---------------------------------------------------------------------------
// LayerNorm row (fp32 or bf16 input) -> bf16 row. One block per row, C=1024.
// ---------------------------------------------------------------------------
template <typename T>
__global__ __launch_bounds__(256) void ln_row(const T* __restrict__ x,
                                              const float* __restrict__ g,
                                              const float* __restrict__ be,
                                              bf16* __restrict__ out) {
    const int row = blockIdx.x, t = threadIdx.x;
    const T* xr = x + (size_t)row * Cn;
    float v[4], s = 0.f, s2 = 0.f;
#pragma unroll
    for (int i = 0; i < 4; i++) {
        v[i] = (float)xr[t + i * 256];
        s += v[i];
        s2 += v[i] * v[i];
    }
#pragma unroll
    for (int off = 32; off > 0; off >>= 1) {
        s += __shfl_down(s, off);
        s2 += __shfl_down(s2, off);
    }
    __shared__ float red[8];
    const int wave = t >> 6, lane = t & 63;
    if (lane == 0) {
        red[wave] = s;
        red[4 + wave] = s2;
    }
    __syncthreads();
    s = red[0] + red[1] + red[2] + red[3];
    s2 = red[4] + red[5] + red[6] + red[7];
    const float mu = s * (1.f / Cn);
    const float rstd = rsqrtf(s2 * (1.f / Cn) - mu * mu + 1e-5f);
    bf16* orow = out + (size_t)row * Cn;
#pragma unroll
    for (int i = 0; i < 4; i++) {
        int c = t + i * 256;
        orow[c] = (bf16)((v[i] - mu) * rstd * g[c] + be[c]);
    }
}

// ---------------------------------------------------------------------------
// V transpose: qkv v-part [B,T,H,64] -> Vt [B,H,64,T]
// ---------------------------------------------------------------------------
__global__ __launch_bounds__(256) void vtrans(const bf16* __restrict__ qkv,
                                              bf16* __restrict__ Vt) {
    __shared__ bf16 tile[64 * 72];
    const int tid = threadIdx.x;
    const int bh = blockIdx.x, b = bh >> 4, h = bh & 15;
    const int t0 = blockIdx.y * 64;
    const int r = tid >> 3, c = (tid & 7) * 8;
#pragma unroll
    for (int i = 0; i < 2; i++) {
        const int rr = r + i * 32;
        *(bf16x8*)(tile + rr * 72 + c) =
            *(const bf16x8*)(qkv + ((size_t)(b * Tn + t0 + rr)) * 3072 + 2 * Cn + h * 64 + c);
    }
    __syncthreads();
#pragma unroll
    for (int i = 0; i < 2; i++) {
        const int d = r + i * 32;
        bf16x8 v;
#pragma unroll
        for (int j = 0; j < 8; j++) v[j] = tile[(c + j) * 72 + d];
        *(bf16x8*)(Vt + ((size_t)bh * 64 + d) * Tn + t0 + c) = v;
    }
}

// ---------------------------------------------------------------------------
// GEMM: out[M,N] = A[M,K] @ Bt[N,K]^T + bias (+ relu) (+ resid)
// TMx128 tile, BK=64, 4 waves, global_load_lds w16 staging, XOR-swizzled LDS
// (16B chunk c of row r stored at phys chunk c^(r&7) -> conflict-free b128).
// ---------------------------------------------------------------------------
template <int TM, bool RELU, bool RESID, bool OUTBF16, typename RT>
__global__ __launch_bounds__(256) void gemm_bt(const bf16* __restrict__ A,
                                               const bf16* __restrict__ Bt,
                                               const float* __restrict__ bias,
                                               const RT* __restrict__ resid,
                                               void* __restrict__ outp,
                                               int M, int N, int K) {
    constexpr int MI = TM / 32;  // m-tiles per wave
    constexpr int AJ = TM / 32;  // A staging instrs per wave
    __shared__ __align__(16) bf16 As[TM * 64];
    __shared__ __align__(16) bf16 Bs[128 * 64];
    const int t = threadIdx.x;
    const int lane = t & 63, wave = t >> 6;
    const int lane15 = lane & 15, quad = lane >> 4;
    const int m0 = blockIdx.x * TM, n0 = blockIdx.y * 128;
    const int mb = (wave >> 1) * (TM / 2), nb = (wave & 1) * 64;

    const f32x4 zero4 = {0.f, 0.f, 0.f, 0.f};
    f32x4 acc[MI][4];
#pragma unroll
    for (int i = 0; i < MI; i++)
#pragma unroll
        for (int j = 0; j < 4; j++) acc[i][j] = zero4;

    // staging: each gload = 1024B = 8 rows x 128B; lane l -> row +(l>>3),
    // phys chunk l&7 holds logical chunk (l&7)^(l>>3)
    const int grow = lane >> 3;
    const int gcol = ((lane & 7) ^ grow) * 8;
    const bf16* gA = A + (size_t)(m0 + wave * (AJ * 8) + grow) * K + gcol;
    const bf16* gB = Bt + (size_t)(n0 + wave * 32 + grow) * K + gcol;
    bf16* lA = As + (wave * AJ) * 512;
    bf16* lB = Bs + (wave * 4) * 512;

    for (int kt = 0; kt < K; kt += 64) {
#pragma unroll
        for (int j = 0; j < AJ; j++)
            gload_lds16(gA + (size_t)(j * 8) * K + kt, lA + j * 512);
#pragma unroll
        for (int j = 0; j < 4; j++)
            gload_lds16(gB + (size_t)(j * 8) * K + kt, lB + j * 512);
        __syncthreads();
#pragma unroll
        for (int kk = 0; kk < 2; kk++) {
            bf16x8 fa[MI], fb[4];
#pragma unroll
            for (int mi = 0; mi < MI; mi++) {
                const int r = mb + mi * 16 + lane15;
                fa[mi] = *(const bf16x8*)(As + r * 64 + (((kk * 4 + quad) ^ (r & 7)) * 8));
            }
#pragma unroll
            for (int ni = 0; ni < 4; ni++) {
                const int r = nb + ni * 16 + lane15;
                fb[ni] = *(const bf16x8*)(Bs + r * 64 + (((kk * 4 + quad) ^ (r & 7)) * 8));
            }
#pragma unroll
            for (int mi = 0; mi < MI; mi++)
#pragma unroll
                for (int ni = 0; ni < 4; ni++)
                    acc[mi][ni] = MFMA16(fa[mi], fb[ni], acc[mi][ni]);
        }
        __syncthreads();
    }

    float bsv[4];
#pragma unroll
    for (int ni = 0; ni < 4; ni++) bsv[ni] = bias[n0 + nb + ni * 16 + lane15];
#pragma unroll
    for (int mi = 0; mi < MI; mi++) {
#pragma unroll
        for (int reg = 0; reg < 4; reg++) {
            const int row = m0 + mb + mi * 16 + quad * 4 + reg;
#pragma unroll
            for (int ni = 0; ni < 4; ni++) {
                const int col = n0 + nb + ni * 16 + lane15;
                float v = acc[mi][ni][reg] + bsv[ni];
                if (RELU) v = v > 0.f ? v : 0.f;
                if (RESID) v += (float)resid[(size_t)row * N + col];
                if (OUTBF16)
                    ((bf16*)outp)[(size_t)row * N + col] = (bf16)v;
                else
                    ((float*)outp)[(size_t)row * N + col] = v;
            }
        }
    }
}

// ---------------------------------------------------------------------------
// Flash attention, causal. Q-tile 128 rows/block (32/wave), K-block 64.
// No max-tracking (bounded logits); row-sum via ones-row appended to V.
// ---------------------------------------------------------------------------
__global__ __launch_bounds__(256) void attn(const bf16* __restrict__ qkv,
                                            const bf16* __restrict__ Vt,
                                            bf16* __restrict__ y) {
    __shared__ __align__(16) bf16 Ks[64 * 72];
    __shared__ __align__(16) bf16 Vs[80 * 72];
    __shared__ __align__(16) bf16 Ps[4][32 * 72];
    const int tid = threadIdx.x, lane = tid & 63, wave = tid >> 6;
    const int lane15 = lane & 15, quad = lane >> 4;
    const int b = blockIdx.x >> 4, h = blockIdx.x & 15;
    const int q0 = blockIdx.y * 128;
    const int qr0 = q0 + wave * 32;
    const float c1 = 0.10412043f;  // (1/sqrt(192)) * log2(e)

    for (int i = tid; i < 16 * 72; i += 256)
        Vs[64 * 72 + i] = (bf16)((i < 72) ? 1.0f : 0.0f);

    bf16x8 fq[2][2];
#pragma unroll
    for (int mi = 0; mi < 2; mi++) {
        const size_t qb = ((size_t)(b * Tn + qr0 + mi * 16 + lane15)) * 3072 + h * 64;
#pragma unroll
        for (int kk = 0; kk < 2; kk++)
            fq[mi][kk] = *(const bf16x8*)(qkv + qb + kk * 32 + quad * 8);
    }

    const f32x4 zero4 = {0.f, 0.f, 0.f, 0.f};
    f32x4 o[2][4], lacc[2];
#pragma unroll
    for (int mi = 0; mi < 2; mi++) {
        lacc[mi] = zero4;
#pragma unroll
        for (int ni = 0; ni < 4; ni++) o[mi][ni] = zero4;
    }

    const int sr = tid >> 3, sc = (tid & 7) * 8;
    const int nkb = q0 / 64 + 2;
    for (int kb = 0; kb < nkb; kb++) {
        const int k0 = kb * 64;
#pragma unroll
        for (int i = 0; i < 2; i++) {
            const int r = sr + i * 32;
            *(bf16x8*)(Ks + r * 72 + sc) =
                *(const bf16x8*)(qkv + ((size_t)(b * Tn + k0 + r)) * 3072 + Cn + h * 64 + sc);
            *(bf16x8*)(Vs + r * 72 + sc) =
                *(const bf16x8*)(Vt + ((size_t)blockIdx.x * 64 + r) * Tn + k0 + sc);
        }
        __syncthreads();

        if (k0 <= qr0 + 31) {
            bf16x8 fk[4][2];
#pragma unroll
            for (int ni = 0; ni < 4; ni++)
#pragma unroll
                for (int kk = 0; kk < 2; kk++)
                    fk[ni][kk] = *(const bf16x8*)(Ks + (ni * 16 + lane15) * 72 + kk * 32 + quad * 8);
            f32x4 s[2][4];
#pragma unroll
            for (int mi = 0; mi < 2; mi++)
#pragma unroll
                for (int ni = 0; ni < 4; ni++) {
                    if (k0 + ni * 16 <= qr0 + mi * 16 + 15) {  // tile not fully masked
                        f32x4 a = zero4;
                        a = MFMA16(fq[mi][0], fk[ni][0], a);
                        a = MFMA16(fq[mi][1], fk[ni][1], a);
                        s[mi][ni] = a;
                    }
                }
            const bool domask = (k0 + 63 > qr0);
            if (domask) {
#pragma unroll
                for (int mi = 0; mi < 2; mi++)
#pragma unroll
                    for (int ni = 0; ni < 4; ni++) {
                        bf16* pd = &Ps[wave][(mi * 16 + quad * 4) * 72 + ni * 16 + lane15];
                        if (k0 + ni * 16 > qr0 + mi * 16 + 15) {  // fully masked
#pragma unroll
                            for (int r = 0; r < 4; r++) pd[r * 72] = (bf16)0.f;
                        } else if (k0 + ni * 16 + 15 <= qr0 + mi * 16) {  // fully valid
#pragma unroll
                            for (int r = 0; r < 4; r++)
                                pd[r * 72] = (bf16)__builtin_amdgcn_exp2f(s[mi][ni][r] * c1);
                        } else {
                            const int key = k0 + ni * 16 + lane15;
                            const int row0 = qr0 + mi * 16 + quad * 4;
#pragma unroll
                            for (int r = 0; r < 4; r++) {
                                float L = (key > row0 + r) ? -1e30f : s[mi][ni][r] * c1;
                                pd[r * 72] = (bf16)__builtin_amdgcn_exp2f(L);
                            }
                        }
                    }
            } else {
#pragma unroll
                for (int mi = 0; mi < 2; mi++)
#pragma unroll
                    for (int ni = 0; ni < 4; ni++)
#pragma unroll
                        for (int r = 0; r < 4; r++)
                            Ps[wave][(mi * 16 + quad * 4 + r) * 72 + ni * 16 + lane15] =
                                (bf16)__builtin_amdgcn_exp2f(s[mi][ni][r] * c1);
            }
            bf16x8 fp[2][2];
#pragma unroll
            for (int mi = 0; mi < 2; mi++)
#pragma unroll
                for (int kk = 0; kk < 2; kk++)
                    fp[mi][kk] = *(const bf16x8*)(&Ps[wave][(mi * 16 + lane15) * 72 + kk * 32 + quad * 8]);
            const bool use_kk1 = (k0 + 32 <= qr0 + 31);  // keys 32..63 reach any row?
#pragma unroll
            for (int ni = 0; ni < 5; ni++) {
                bf16x8 fv0 = *(const bf16x8*)(Vs + (ni * 16 + lane15) * 72 + quad * 8);
                bf16x8 fv1 = *(const bf16x8*)(Vs + (ni * 16 + lane15) * 72 + 32 + quad * 8);
#pragma unroll
                for (int mi = 0; mi < 2; mi++) {
                    f32x4* dst = (ni < 4) ? &o[mi][ni] : &lacc[mi];
                    f32x4 a = *dst;
                    a = MFMA16(fp[mi][0], fv0, a);
                    if (use_kk1) a = MFMA16(fp[mi][1], fv1, a);
                    *dst = a;
                }
            }
        }
        __syncthreads();
    }

#pragma unroll
    for (int mi = 0; mi < 2; mi++)
#pragma unroll
        for (int r = 0; r < 4; r++) {
            float l = __shfl(lacc[mi][r], lane & 48);
            const float inv = 1.f / l;
            const size_t base = ((size_t)(b * Tn + qr0 + mi * 16 + quad * 4 + r)) * Cn + h * 64;
#pragma unroll
            for (int ni = 0; ni < 4; ni++)
                y[base + ni * 16 + lane15] = (bf16)(o[mi][ni][r] * inv);
        }
}

// ---------------------------------------------------------------------------
extern "C" void kernel_launch(void* const* d_in, const int* in_sizes, int n_in,
                              void* d_out, int out_size, void* d_ws, size_t ws_size,
                              hipStream_t stream) {
    const float* x = (const float*)d_in[0];
    const float* Wqkv = (const float*)d_in[1];
    const float* bqkv = (const float*)d_in[2];
    const float* Wproj = (const float*)d_in[3];
    const float* bproj = (const float*)d_in[4];
    const float* ln1g = (const float*)d_in[5];
    const float* ln1b = (const float*)d_in[6];
    const float* ln2g = (const float*)d_in[7];
    const float* ln2b = (const float*)d_in[8];
    const float* W1 = (const float*)d_in[9];
    const float* b1 = (const float*)d_in[10];
    const float* W2 = (const float*)d_in[11];
    const float* b2 = (const float*)d_in[12];
    float* out = (float*)d_out;

    char* ws = (char*)d_ws;
    size_t off = 0;
    auto alloc = [&](size_t bytes) {
        void* p = ws + off;
        off += (bytes + 255) & ~(size_t)255;
        return p;
    };
    bf16* WqkvT = (bf16*)alloc((size_t)3072 * 1024 * 2);
    bf16* WprojT = (bf16*)alloc((size_t)1024 * 1024 * 2);
    bf16* W1T = (bf16*)alloc((size_t)4096 * 1024 * 2);
    bf16* W2T = (bf16*)alloc((size_t)1024 * 4096 * 2);
    bf16* hbuf = (bf16*)alloc((size_t)8192 * 1024 * 2);
    bf16* qkvb = (bf16*)alloc((size_t)8192 * 3072 * 2);
    bf16* ybuf = (bf16*)alloc((size_t)8192 * 1024 * 2);
    bf16* vtb = (bf16*)alloc((size_t)8192 * 1024 * 2);
    bf16* x1b = (bf16*)alloc((size_t)8192 * 1024 * 2);
    bf16* a1 = qkvb;  // reuse qkv(48MB)+y(16MB) region for a1 (64MB); both dead by MLP1

    tcast<<<dim3(3072 / 32, 1024 / 32), 256, 0, stream>>>(Wqkv, WqkvT, 1024, 3072);
    tcast<<<dim3(1024 / 32, 1024 / 32), 256, 0, stream>>>(Wproj, WprojT, 1024, 1024);
    tcast<<<dim3(4096 / 32, 1024 / 32), 256, 0, stream>>>(W1, W1T, 1024, 4096);
    tcast<<<dim3(1024 / 32, 4096 / 32), 256, 0, stream>>>(W2, W2T, 4096, 1024);

    // LN1 -> h
    ln_row<float><<<8192, 256, 0, stream>>>(x, ln1g, ln1b, hbuf);
    // qkv = h @ Wqkv + bqkv  (bf16)
    gemm_bt<128, false, false, true, float><<<dim3(64, 24), 256, 0, stream>>>(
        hbuf, WqkvT, bqkv, (const float*)nullptr, qkvb, 8192, 3072, 1024);
    // V -> Vt [B,H,64,T]
    vtrans<<<dim3(Bn * Hn, Tn / 64), 256, 0, stream>>>(qkvb, vtb);
    // attention -> y (bf16)
    attn<<<dim3(Bn * Hn, Tn / 128), 256, 0, stream>>>(qkvb, vtb, ybuf);
    // x1 = x + y @ Wproj + bproj  (bf16)
    gemm_bt<64, false, true, true, float><<<dim3(128, 8), 256, 0, stream>>>(
        ybuf, WprojT, bproj, x, x1b, 8192, 1024, 1024);
    // LN2 -> h
    ln_row<bf16><<<8192, 256, 0, stream>>>(x1b, ln2g, ln2b, hbuf);
    // a1 = relu(h @ W1 + b1)  (bf16)
    gemm_bt<128, true, false, true, float><<<dim3(64, 32), 256, 0, stream>>>(
        hbuf, W1T, b1, (const float*)nullptr, a1, 8192, 4096, 1024);
    // out = x1 + a1 @ W2 + b2  (fp32)
    gemm_bt<64, false, true, false, bf16><<<dim3(128, 8), 256, 0, stream>>>(
        a1, W2T, b2, x1b, out, 8192, 1024, 4096);
}

// Round 4
// 435.419 us; speedup vs baseline: 1.3019x; 1.0773x over previous
//
#include <hip/hip_runtime.h>

typedef __bf16 bf16;
typedef __bf16 bf16x8 __attribute__((ext_vector_type(8)));
typedef float f32x4 __attribute__((ext_vector_type(4)));

#define MFMA16(a, b, c) __builtin_amdgcn_mfma_f32_16x16x32_bf16(a, b, c, 0, 0, 0)

static constexpr int Bn = 8;
static constexpr int Tn = 1024;
static constexpr int Cn = 1024;
static constexpr int Hn = 16;

typedef const __attribute__((address_space(1))) unsigned int* gp_t;
typedef __attribute__((address_space(3))) unsigned int* lp_t;
__device__ __forceinline__ void gload_lds16(const bf16* g, bf16* l) {
    __builtin_amdgcn_global_load_lds((gp_t)(const void*)g, (lp_t)(void*)l, 16, 0, 0);
}

// ---------------------------------------------------------------------------
// Transpose + cast fp32 [K][N] -> bf16 [N][K]
// ---------------------------------------------------------------------------
__global__ __launch_bounds__(256) void tcast(const float* __restrict__ in,
                                             bf16* __restrict__ out,
                                             int K, int N) {
    __shared__ float tile[32][33];
    const int n0 = blockIdx.x * 32, k0 = blockIdx.y * 32;
    const int tx = threadIdx.x & 31, ty = threadIdx.x >> 5;  // 32 x 8
#pragma unroll
    for (int i = 0; i < 4; i++)
        tile[ty + 8 * i][tx] = in[(size_t)(k0 + ty + 8 * i) * N + n0 + tx];
    __syncthreads();
#pragma unroll
    for (int i = 0; i < 4; i++)
        out[(size_t)(n0 + ty + 8 * i) * K + k0 + tx] = (bf16)tile[tx][ty + 8 * i];
}

// ---------------------------------------------------------------------------
// LayerNorm row (fp32 or bf16 input) -> bf16 row. One block per row, C=1024.
// ---------------------------------------------------------------------------
template <typename T>
__global__ __launch_bounds__(256) void ln_row(const T* __restrict__ x,
                                              const float* __restrict__ g,
                                              const float* __restrict__ be,
                                              bf16* __restrict__ out) {
    const int row = blockIdx.x, t = threadIdx.x;
    const T* xr = x + (size_t)row * Cn;
    float v[4], s = 0.f, s2 = 0.f;
#pragma unroll
    for (int i = 0; i < 4; i++) {
        v[i] = (float)xr[t + i * 256];
        s += v[i];
        s2 += v[i] * v[i];
    }
#pragma unroll
    for (int off = 32; off > 0; off >>= 1) {
        s += __shfl_down(s, off);
        s2 += __shfl_down(s2, off);
    }
    __shared__ float red[8];
    const int wave = t >> 6, lane = t & 63;
    if (lane == 0) {
        red[wave] = s;
        red[4 + wave] = s2;
    }
    __syncthreads();
    s = red[0] + red[1] + red[2] + red[3];
    s2 = red[4] + red[5] + red[6] + red[7];
    const float mu = s * (1.f / Cn);
    const float rstd = rsqrtf(s2 * (1.f / Cn) - mu * mu + 1e-5f);
    bf16* orow = out + (size_t)row * Cn;
#pragma unroll
    for (int i = 0; i < 4; i++) {
        int c = t + i * 256;
        orow[c] = (bf16)((v[i] - mu) * rstd * g[c] + be[c]);
    }
}

// ---------------------------------------------------------------------------
// V transpose: qkv v-part [B,T,H,64] -> Vt [B,H,64,T]
// ---------------------------------------------------------------------------
__global__ __launch_bounds__(256) void vtrans(const bf16* __restrict__ qkv,
                                              bf16* __restrict__ Vt) {
    __shared__ bf16 tile[64 * 72];
    const int tid = threadIdx.x;
    const int bh = blockIdx.x, b = bh >> 4, h = bh & 15;
    const int t0 = blockIdx.y * 64;
    const int r = tid >> 3, c = (tid & 7) * 8;
#pragma unroll
    for (int i = 0; i < 2; i++) {
        const int rr = r + i * 32;
        *(bf16x8*)(tile + rr * 72 + c) =
            *(const bf16x8*)(qkv + ((size_t)(b * Tn + t0 + rr)) * 3072 + 2 * Cn + h * 64 + c);
    }
    __syncthreads();
#pragma unroll
    for (int i = 0; i < 2; i++) {
        const int d = r + i * 32;
        bf16x8 v;
#pragma unroll
        for (int j = 0; j < 8; j++) v[j] = tile[(c + j) * 72 + d];
        *(bf16x8*)(Vt + ((size_t)bh * 64 + d) * Tn + t0 + c) = v;
    }
}

// ---------------------------------------------------------------------------
// GEMM: out[M,N] = A[M,K] @ Bt[N,K]^T + bias (+ relu) (+ resid)
// TMxTN tile, BK=64, 4 waves (2x2), wave tile (TM/2)x(TN/2).
// global_load_lds w16 staging, XOR-swizzled LDS (chunk c of row r at phys
// chunk c^(r&7)) -> conflict-free ds_read_b128.
// ---------------------------------------------------------------------------
template <int TM, int TN, bool RELU, bool RESID, bool OUTBF16, typename RT>
__global__ __launch_bounds__(256, 2) void gemm_bt(const bf16* __restrict__ A,
                                                  const bf16* __restrict__ Bt,
                                                  const float* __restrict__ bias,
                                                  const RT* __restrict__ resid,
                                                  void* __restrict__ outp,
                                                  int M, int N, int K) {
    constexpr int MI = TM / 32;  // m 16-tiles per wave
    constexpr int NI = TN / 32;  // n 16-tiles per wave
    constexpr int AJ = TM / 32;  // A gloads per wave
    constexpr int BJ = TN / 32;  // B gloads per wave
    __shared__ __align__(16) bf16 As[TM * 64];
    __shared__ __align__(16) bf16 Bs[TN * 64];
    const int t = threadIdx.x;
    const int lane = t & 63, wave = t >> 6;
    const int lane15 = lane & 15, quad = lane >> 4;
    const int m0 = blockIdx.x * TM, n0 = blockIdx.y * TN;
    const int mb = (wave >> 1) * (TM / 2), nb = (wave & 1) * (TN / 2);

    const f32x4 zero4 = {0.f, 0.f, 0.f, 0.f};
    f32x4 acc[MI][NI];
#pragma unroll
    for (int i = 0; i < MI; i++)
#pragma unroll
        for (int j = 0; j < NI; j++) acc[i][j] = zero4;

    // staging: each gload = 1024B = 8 rows x 128B; lane l -> row +(l>>3),
    // phys chunk l&7 holds logical chunk (l&7)^(l>>3)
    const int grow = lane >> 3;
    const int gcol = ((lane & 7) ^ grow) * 8;
    const bf16* gA = A + (size_t)(m0 + wave * (AJ * 8) + grow) * K + gcol;
    const bf16* gB = Bt + (size_t)(n0 + wave * (BJ * 8) + grow) * K + gcol;
    bf16* lA = As + (wave * AJ) * 512;
    bf16* lB = Bs + (wave * BJ) * 512;

    for (int kt = 0; kt < K; kt += 64) {
#pragma unroll
        for (int j = 0; j < AJ; j++)
            gload_lds16(gA + (size_t)(j * 8) * K + kt, lA + j * 512);
#pragma unroll
        for (int j = 0; j < BJ; j++)
            gload_lds16(gB + (size_t)(j * 8) * K + kt, lB + j * 512);
        __syncthreads();
#pragma unroll
        for (int kk = 0; kk < 2; kk++) {
            bf16x8 fa[MI], fb[NI];
#pragma unroll
            for (int mi = 0; mi < MI; mi++) {
                const int r = mb + mi * 16 + lane15;
                fa[mi] = *(const bf16x8*)(As + r * 64 + (((kk * 4 + quad) ^ (r & 7)) * 8));
            }
#pragma unroll
            for (int ni = 0; ni < NI; ni++) {
                const int r = nb + ni * 16 + lane15;
                fb[ni] = *(const bf16x8*)(Bs + r * 64 + (((kk * 4 + quad) ^ (r & 7)) * 8));
            }
#pragma unroll
            for (int mi = 0; mi < MI; mi++)
#pragma unroll
                for (int ni = 0; ni < NI; ni++)
                    acc[mi][ni] = MFMA16(fa[mi], fb[ni], acc[mi][ni]);
        }
        __syncthreads();
    }

    float bsv[NI];
#pragma unroll
    for (int ni = 0; ni < NI; ni++) bsv[ni] = bias[n0 + nb + ni * 16 + lane15];
#pragma unroll
    for (int mi = 0; mi < MI; mi++) {
#pragma unroll
        for (int reg = 0; reg < 4; reg++) {
            const int row = m0 + mb + mi * 16 + quad * 4 + reg;
#pragma unroll
            for (int ni = 0; ni < NI; ni++) {
                const int col = n0 + nb + ni * 16 + lane15;
                float v = acc[mi][ni][reg] + bsv[ni];
                if (RELU) v = v > 0.f ? v : 0.f;
                if (RESID) v += (float)resid[(size_t)row * N + col];
                if (OUTBF16)
                    ((bf16*)outp)[(size_t)row * N + col] = (bf16)v;
                else
                    ((float*)outp)[(size_t)row * N + col] = v;
            }
        }
    }
}

// ---------------------------------------------------------------------------
// Flash attention, causal. Q-tile 128 rows/block (32/wave), K-block 64.
// No max-tracking (bounded logits); row-sum via ones-row appended to V.
// ---------------------------------------------------------------------------
__global__ __launch_bounds__(256) void attn(const bf16* __restrict__ qkv,
                                            const bf16* __restrict__ Vt,
                                            bf16* __restrict__ y) {
    __shared__ __align__(16) bf16 Ks[64 * 72];
    __shared__ __align__(16) bf16 Vs[80 * 72];
    __shared__ __align__(16) bf16 Ps[4][32 * 72];
    const int tid = threadIdx.x, lane = tid & 63, wave = tid >> 6;
    const int lane15 = lane & 15, quad = lane >> 4;
    const int b = blockIdx.x >> 4, h = blockIdx.x & 15;
    const int q0 = blockIdx.y * 128;
    const int qr0 = q0 + wave * 32;
    const float c1 = 0.10412043f;  // (1/sqrt(192)) * log2(e)

    for (int i = tid; i < 16 * 72; i += 256)
        Vs[64 * 72 + i] = (bf16)((i < 72) ? 1.0f : 0.0f);

    bf16x8 fq[2][2];
#pragma unroll
    for (int mi = 0; mi < 2; mi++) {
        const size_t qb = ((size_t)(b * Tn + qr0 + mi * 16 + lane15)) * 3072 + h * 64;
#pragma unroll
        for (int kk = 0; kk < 2; kk++)
            fq[mi][kk] = *(const bf16x8*)(qkv + qb + kk * 32 + quad * 8);
    }

    const f32x4 zero4 = {0.f, 0.f, 0.f, 0.f};
    f32x4 o[2][4], lacc[2];
#pragma unroll
    for (int mi = 0; mi < 2; mi++) {
        lacc[mi] = zero4;
#pragma unroll
        for (int ni = 0; ni < 4; ni++) o[mi][ni] = zero4;
    }

    const int sr = tid >> 3, sc = (tid & 7) * 8;
    const int nkb = q0 / 64 + 2;
    for (int kb = 0; kb < nkb; kb++) {
        const int k0 = kb * 64;
#pragma unroll
        for (int i = 0; i < 2; i++) {
            const int r = sr + i * 32;
            *(bf16x8*)(Ks + r * 72 + sc) =
                *(const bf16x8*)(qkv + ((size_t)(b * Tn + k0 + r)) * 3072 + Cn + h * 64 + sc);
            *(bf16x8*)(Vs + r * 72 + sc) =
                *(const bf16x8*)(Vt + ((size_t)blockIdx.x * 64 + r) * Tn + k0 + sc);
        }
        __syncthreads();

        if (k0 <= qr0 + 31) {
            bf16x8 fk[4][2];
#pragma unroll
            for (int ni = 0; ni < 4; ni++)
#pragma unroll
                for (int kk = 0; kk < 2; kk++)
                    fk[ni][kk] = *(const bf16x8*)(Ks + (ni * 16 + lane15) * 72 + kk * 32 + quad * 8);
            f32x4 s[2][4];
#pragma unroll
            for (int mi = 0; mi < 2; mi++)
#pragma unroll
                for (int ni = 0; ni < 4; ni++) {
                    if (k0 + ni * 16 <= qr0 + mi * 16 + 15) {  // tile not fully masked
                        f32x4 a = zero4;
                        a = MFMA16(fq[mi][0], fk[ni][0], a);
                        a = MFMA16(fq[mi][1], fk[ni][1], a);
                        s[mi][ni] = a;
                    }
                }
            const bool domask = (k0 + 63 > qr0);
            if (domask) {
#pragma unroll
                for (int mi = 0; mi < 2; mi++)
#pragma unroll
                    for (int ni = 0; ni < 4; ni++) {
                        bf16* pd = &Ps[wave][(mi * 16 + quad * 4) * 72 + ni * 16 + lane15];
                        if (k0 + ni * 16 > qr0 + mi * 16 + 15) {  // fully masked
#pragma unroll
                            for (int r = 0; r < 4; r++) pd[r * 72] = (bf16)0.f;
                        } else if (k0 + ni * 16 + 15 <= qr0 + mi * 16) {  // fully valid
#pragma unroll
                            for (int r = 0; r < 4; r++)
                                pd[r * 72] = (bf16)__builtin_amdgcn_exp2f(s[mi][ni][r] * c1);
                        } else {
                            const int key = k0 + ni * 16 + lane15;
                            const int row0 = qr0 + mi * 16 + quad * 4;
#pragma unroll
                            for (int r = 0; r < 4; r++) {
                                float L = (key > row0 + r) ? -1e30f : s[mi][ni][r] * c1;
                                pd[r * 72] = (bf16)__builtin_amdgcn_exp2f(L);
                            }
                        }
                    }
            } else {
#pragma unroll
                for (int mi = 0; mi < 2; mi++)
#pragma unroll
                    for (int ni = 0; ni < 4; ni++)
#pragma unroll
                        for (int r = 0; r < 4; r++)
                            Ps[wave][(mi * 16 + quad * 4 + r) * 72 + ni * 16 + lane15] =
                                (bf16)__builtin_amdgcn_exp2f(s[mi][ni][r] * c1);
            }
            bf16x8 fp[2][2];
#pragma unroll
            for (int mi = 0; mi < 2; mi++)
#pragma unroll
                for (int kk = 0; kk < 2; kk++)
                    fp[mi][kk] = *(const bf16x8*)(&Ps[wave][(mi * 16 + lane15) * 72 + kk * 32 + quad * 8]);
            const bool use_kk1 = (k0 + 32 <= qr0 + 31);
#pragma unroll
            for (int ni = 0; ni < 5; ni++) {
                bf16x8 fv0 = *(const bf16x8*)(Vs + (ni * 16 + lane15) * 72 + quad * 8);
                bf16x8 fv1 = *(const bf16x8*)(Vs + (ni * 16 + lane15) * 72 + 32 + quad * 8);
#pragma unroll
                for (int mi = 0; mi < 2; mi++) {
                    f32x4* dst = (ni < 4) ? &o[mi][ni] : &lacc[mi];
                    f32x4 a = *dst;
                    a = MFMA16(fp[mi][0], fv0, a);
                    if (use_kk1) a = MFMA16(fp[mi][1], fv1, a);
                    *dst = a;
                }
            }
        }
        __syncthreads();
    }

#pragma unroll
    for (int mi = 0; mi < 2; mi++)
#pragma unroll
        for (int r = 0; r < 4; r++) {
            float l = __shfl(lacc[mi][r], lane & 48);
            const float inv = 1.f / l;
            const size_t base = ((size_t)(b * Tn + qr0 + mi * 16 + quad * 4 + r)) * Cn + h * 64;
#pragma unroll
            for (int ni = 0; ni < 4; ni++)
                y[base + ni * 16 + lane15] = (bf16)(o[mi][ni][r] * inv);
        }
}

// ---------------------------------------------------------------------------
extern "C" void kernel_launch(void* const* d_in, const int* in_sizes, int n_in,
                              void* d_out, int out_size, void* d_ws, size_t ws_size,
                              hipStream_t stream) {
    const float* x = (const float*)d_in[0];
    const float* Wqkv = (const float*)d_in[1];
    const float* bqkv = (const float*)d_in[2];
    const float* Wproj = (const float*)d_in[3];
    const float* bproj = (const float*)d_in[4];
    const float* ln1g = (const float*)d_in[5];
    const float* ln1b = (const float*)d_in[6];
    const float* ln2g = (const float*)d_in[7];
    const float* ln2b = (const float*)d_in[8];
    const float* W1 = (const float*)d_in[9];
    const float* b1 = (const float*)d_in[10];
    const float* W2 = (const float*)d_in[11];
    const float* b2 = (const float*)d_in[12];
    float* out = (float*)d_out;

    char* ws = (char*)d_ws;
    size_t off = 0;
    auto alloc = [&](size_t bytes) {
        void* p = ws + off;
        off += (bytes + 255) & ~(size_t)255;
        return p;
    };
    bf16* WqkvT = (bf16*)alloc((size_t)3072 * 1024 * 2);
    bf16* WprojT = (bf16*)alloc((size_t)1024 * 1024 * 2);
    bf16* W1T = (bf16*)alloc((size_t)4096 * 1024 * 2);
    bf16* W2T = (bf16*)alloc((size_t)1024 * 4096 * 2);
    bf16* hbuf = (bf16*)alloc((size_t)8192 * 1024 * 2);
    bf16* qkvb = (bf16*)alloc((size_t)8192 * 3072 * 2);
    bf16* ybuf = (bf16*)alloc((size_t)8192 * 1024 * 2);
    bf16* vtb = (bf16*)alloc((size_t)8192 * 1024 * 2);
    bf16* x1b = (bf16*)alloc((size_t)8192 * 1024 * 2);
    bf16* a1 = qkvb;  // reuse qkv(48MB)+y(16MB) region for a1 (64MB); both dead by MLP1

    tcast<<<dim3(3072 / 32, 1024 / 32), 256, 0, stream>>>(Wqkv, WqkvT, 1024, 3072);
    tcast<<<dim3(1024 / 32, 1024 / 32), 256, 0, stream>>>(Wproj, WprojT, 1024, 1024);
    tcast<<<dim3(4096 / 32, 1024 / 32), 256, 0, stream>>>(W1, W1T, 1024, 4096);
    tcast<<<dim3(1024 / 32, 4096 / 32), 256, 0, stream>>>(W2, W2T, 4096, 1024);

    // LN1 -> h
    ln_row<float><<<8192, 256, 0, stream>>>(x, ln1g, ln1b, hbuf);
    // qkv = h @ Wqkv + bqkv  (bf16)   TM=128, TN=256 (wave 64x128)
    gemm_bt<128, 256, false, false, true, float><<<dim3(64, 12), 256, 0, stream>>>(
        hbuf, WqkvT, bqkv, (const float*)nullptr, qkvb, 8192, 3072, 1024);
    // V -> Vt [B,H,64,T]
    vtrans<<<dim3(Bn * Hn, Tn / 64), 256, 0, stream>>>(qkvb, vtb);
    // attention -> y (bf16)
    attn<<<dim3(Bn * Hn, Tn / 128), 256, 0, stream>>>(qkvb, vtb, ybuf);
    // x1 = x + y @ Wproj + bproj  (bf16)   TM=128, TN=128 (grid 512 for 2 blk/CU)
    gemm_bt<128, 128, false, true, true, float><<<dim3(64, 8), 256, 0, stream>>>(
        ybuf, WprojT, bproj, x, x1b, 8192, 1024, 1024);
    // LN2 -> h
    ln_row<bf16><<<8192, 256, 0, stream>>>(x1b, ln2g, ln2b, hbuf);
    // a1 = relu(h @ W1 + b1)  (bf16)   TM=128, TN=256
    gemm_bt<128, 256, true, false, true, float><<<dim3(64, 16), 256, 0, stream>>>(
        hbuf, W1T, b1, (const float*)nullptr, a1, 8192, 4096, 1024);
    // out = x1 + a1 @ W2 + b2  (fp32)   TM=128, TN=128
    gemm_bt<128, 128, false, true, false, bf16><<<dim3(64, 8), 256, 0, stream>>>(
        a1, W2T, b2, x1b, out, 8192, 1024, 4096);
}